// Round 5
// baseline (237.853 us; speedup 1.0000x reference)
//
#include <hip/hip_runtime.h>

#define BB 32
#define TT 128
#define PP 512
#define DD 300
#define KT 10      // K chunks of 32 (KP = 320 = 300 data + bias slot + zeros)
#define NX 7168    // P * 14: full column set, native 14-stride scan layout
#define AT 256     // A tiles (4096/16)
#define BT 448     // B tiles (7168/16)
#define NEG -1e30f

typedef _Float16 half8 __attribute__((ext_vector_type(8)));
typedef float floatx4 __attribute__((ext_vector_type(4)));

__device__ __forceinline__ floatx4 mfma16(half8 a, half8 b, floatx4 c) {
    return __builtin_amdgcn_mfma_f32_16x16x32_f16(a, b, c, 0, 0, 0);
}

// ---------------------------------------------------------------------------
// Pack into MFMA-fragment-blocked layout + error-free f16 Dekker split
// (x = hi + lo*2^-12, lo stored *4096). Chunk (tile16, kt32) = 1KB:
// half idx = lane*8+i, row = tile*16+(lane&15), k = kt*32+(lane>>4)*8+i.
// B rows = diags rows 0..7167 directly (all 14 cols; col 13 output is dead
// but writing it keeps C dense 14-stride). K-slot 300 carries bias
// (A side gets exact 1.0); slots 301..319 zero. UNCHANGED from R0.
// ---------------------------------------------------------------------------
__global__ __launch_bounds__(256) void pack_kernel(
    const int* __restrict__ tokens, const float* __restrict__ emb,
    const float* __restrict__ diags, const float* __restrict__ bias,
    _Float16* __restrict__ AhP, _Float16* __restrict__ AlP,
    _Float16* __restrict__ BhP, _Float16* __restrict__ BlP)
{
    const int idx = blockIdx.x * 256 + threadIdx.x;
    if (idx >= (AT + BT) * KT * 64) return;
    const int chunk = idx >> 6;
    const int ln = idx & 63;

    const float* src;
    float kslot;
    _Float16 *dh, *dl;
    int kt;
    if (chunk < AT * KT) {
        const int mt = chunk / KT; kt = chunk - mt * KT;
        const int m = mt * 16 + (ln & 15);
        src = emb + (size_t)tokens[m] * DD;
        kslot = 1.0f;
        dh = AhP + (size_t)chunk * 512 + ln * 8;
        dl = AlP + (size_t)chunk * 512 + ln * 8;
    } else {
        const int c2 = chunk - AT * KT;
        const int nt = c2 / KT; kt = c2 - nt * KT;
        const int n = nt * 16 + (ln & 15);       // srow = n directly
        src = diags + (size_t)n * DD;
        kslot = bias[n];
        dh = BhP + (size_t)c2 * 512 + ln * 8;
        dl = BlP + (size_t)c2 * 512 + ln * 8;
    }

    const int k0 = kt * 32 + (ln >> 4) * 8;
    float v[8];
    if (k0 + 8 <= DD) {
        float4 a = *(const float4*)(src + k0);
        float4 b = *(const float4*)(src + k0 + 4);
        v[0] = a.x; v[1] = a.y; v[2] = a.z; v[3] = a.w;
        v[4] = b.x; v[5] = b.y; v[6] = b.z; v[7] = b.w;
    } else {
        #pragma unroll
        for (int i = 0; i < 8; ++i) {
            const int k = k0 + i;
            v[i] = (k < DD) ? src[k] : (k == DD ? kslot : 0.f);
        }
    }
    half8 h, l;
    #pragma unroll
    for (int i = 0; i < 8; ++i) {
        h[i] = (_Float16)v[i];
        l[i] = (_Float16)((v[i] - (float)h[i]) * 4096.f);
    }
    *(half8*)dh = h;
    *(half8*)dl = l;
}

// ---------------------------------------------------------------------------
// GEMM, barrier-free (R5). C[m][n] = sum_k A[m][k]*B[n][k], bias in k=300.
// R0 diagnosed stall: s_waitcnt vmcnt(0) drain before each of 10 s_barriers
// (38% MfmaUtil vs ~29us MFMA floor). The barrier existed ONLY for B LDS
// staging — but the B pack is already fragment-blocked, so each wave can
// load its B fragments DIRECTLY global->VGPR (chunk*512 + ln*8 = coalesced
// 16B/lane), exactly like the A path. Cost: B chunks read by 2 waves
// instead of shared via LDS (2x B traffic, L1/L2-resident; B pack = 9MB).
// Gain: ZERO barriers / waitcnt-drains in the K-loop; waves slip freely;
// compiler global-schedules the fully-unrolled loop. MFMA order per
// accumulator identical to R0 -> bit-identical C on stored rows.
// Epilogue-only dead-row guard (R2 lesson: guards INSIDE the K-loop spill;
// after it they can't perturb the schedule): block rows = t 0..127 of batch
// element b = blockIdx.y; skip stores for 16-row tiles with t0 >= dl (scan
// never reads t >= dl). Only wave wm=1 ever branches (dl >= 64).
// ---------------------------------------------------------------------------
__global__ __launch_bounds__(256, 2) void gemm_kernel(
    const _Float16* __restrict__ AhP, const _Float16* __restrict__ AlP,
    const _Float16* __restrict__ BhP, const _Float16* __restrict__ BlP,
    const int* __restrict__ doc_lens,
    float* __restrict__ C)
{
    const int tid = threadIdx.x;
    const int w = tid >> 6, ln = tid & 63;
    const int n0t = blockIdx.x * 8, m0t = blockIdx.y * 8;
    const int wm = w & 1, wn = w >> 1;

    const int dl = doc_lens[blockIdx.y];   // rows of this block = t 0..127 of b

    floatx4 acc0[4][4], acc1[4][4];
    #pragma unroll
    for (int i = 0; i < 4; ++i)
        #pragma unroll
        for (int j = 0; j < 4; ++j) {
            acc0[i][j] = (floatx4){0.f, 0.f, 0.f, 0.f};
            acc1[i][j] = (floatx4){0.f, 0.f, 0.f, 0.f};
        }

    half8 ah[2][4], al[2][4];

    auto loadA = [&](int kt, int pb) {
        #pragma unroll
        for (int i = 0; i < 4; ++i) {
            const size_t ch = ((size_t)(m0t + wm * 4 + i) * KT + kt) * 512 + ln * 8;
            ah[pb][i] = *(const half8*)(AhP + ch);
            al[pb][i] = *(const half8*)(AlP + ch);
        }
    };

    loadA(0, 0);

    #pragma unroll
    for (int kt = 0; kt < KT; ++kt) {
        const int cb = kt & 1, nb = cb ^ 1;
        if (kt + 1 < KT) loadA(kt + 1, nb);
        #pragma unroll
        for (int j = 0; j < 4; ++j) {
            const size_t ch = ((size_t)(n0t + wn * 4 + j) * KT + kt) * 512 + ln * 8;
            const half8 bh = *(const half8*)(BhP + ch);
            const half8 bl = *(const half8*)(BlP + ch);
            #pragma unroll
            for (int i = 0; i < 4; ++i) {
                acc0[i][j] = mfma16(ah[cb][i], bh, acc0[i][j]);
                acc1[i][j] = mfma16(ah[cb][i], bl, acc1[i][j]);
                acc1[i][j] = mfma16(al[cb][i], bh, acc1[i][j]);
            }
        }
    }

    // epilogue: C/D layout col(n)=lane&15, row(m)=(lane>>4)*4+reg.
    // store guard: tile i covers t in [(wm*4+i)*16, +16); dead iff t0 >= dl.
    #pragma unroll
    for (int j = 0; j < 4; ++j) {
        const int n = (n0t + wn * 4 + j) * 16 + (ln & 15);
        #pragma unroll
        for (int i = 0; i < 4; ++i) {
            if ((wm * 4 + i) * 16 < dl) {
                const int mb = (m0t + wm * 4 + i) * 16 + (ln >> 4) * 4;
                #pragma unroll
                for (int r = 0; r < 4; ++r)
                    C[(size_t)(mb + r) * NX + n] =
                        acc0[i][j][r] + acc1[i][j][r] * (1.0f / 4096.0f);
            }
        }
    }
}

// ---------------------------------------------------------------------------
// Max-sum scan (proven ~19us structure, UNCHANGED from R0).
// One thread per (b,p); 14-float 8B-aligned rows, 7x float2 loads, depth-4
// prefetch with STATIC slot indices; dl block-uniform. Rows t >= dl may be
// unwritten (gemm store guard) but are never consumed.
// v[0..6]=self-loop (diag0 l0..6), v[7..12]=main (diag1 l0..5), v[13] dead.
// ---------------------------------------------------------------------------
__global__ __launch_bounds__(64) void scan_kernel(
    const float* __restrict__ ts,
    const float* __restrict__ epsilons,
    const int* __restrict__ doc_lens,
    float* __restrict__ scores)
{
    const int b = blockIdx.x;
    const int p = blockIdx.y * 64 + threadIdx.x;
    const int dl = doc_lens[b];   // in [64, 128]

    float e[6];
    #pragma unroll
    for (int i = 0; i < 6; ++i) e[i] = epsilons[p * 6 + i];

    const float* base = ts + (size_t)b * TT * NX + p * 14;

    float h0 = 0.f, h1 = NEG, h2 = NEG, h3 = NEG, h4 = NEG, h5 = NEG, h6 = NEG;
    float sc = NEG;
    const bool end5 = (p < 256);

    float2 buf[4][7];

    auto load = [&](int slot, int t) {
        const float2* s = (const float2*)(base + (size_t)t * NX);
        #pragma unroll
        for (int i = 0; i < 7; ++i) buf[slot][i] = s[i];
    };
    auto step = [&](int slot) {
        const float2* v = buf[slot];
        float ae0 = h0;
        float ae1 = fmaxf(h1, h0 + e[0]);
        float ae2 = fmaxf(h2, h1 + e[1]);
        float ae3 = fmaxf(h3, h2 + e[2]);
        float ae4 = fmaxf(h4, h3 + e[3]);
        float ae5 = fmaxf(h5, h4 + e[4]);
        float ae6 = fmaxf(h6, h5 + e[5]);
        h0 = fmaxf(0.f,            ae0 + v[0].x);
        h1 = fmaxf(ae0 + v[3].y,   ae1 + v[0].y);
        h2 = fmaxf(ae1 + v[4].x,   ae2 + v[1].x);
        h3 = fmaxf(ae2 + v[4].y,   ae3 + v[1].y);
        h4 = fmaxf(ae3 + v[5].x,   ae4 + v[2].x);
        h5 = fmaxf(ae4 + v[5].y,   ae5 + v[2].y);
        h6 = fmaxf(ae5 + v[6].x,   ae6 + v[3].x);
        sc = fmaxf(sc, end5 ? h5 : h6);   // every executed step has t < dl
    };

    #pragma unroll
    for (int j = 0; j < 4; ++j) load(j, j);

    int tb = 0;
    for (; tb + 4 <= dl; tb += 4) {
        #pragma unroll
        for (int j = 0; j < 4; ++j) {
            step(j);
            const int t = tb + j + 4;
            load(j, t > 127 ? 127 : t);   // clamp: slots past dl never consumed
        }
    }
    const int rem = dl - tb;       // 0..3, block-uniform
    #pragma unroll
    for (int j = 0; j < 3; ++j)
        if (j < rem) step(j);

    scores[p * BB + b] = sc;
}

// ---------------------------------------------------------------------------
// BatchNorm (batch stats) + sign(relu) + final linear. One block. UNCHANGED.
// ---------------------------------------------------------------------------
__global__ __launch_bounds__(512) void finalize_kernel(
    const float* __restrict__ scores,
    const float* __restrict__ bn_w,
    const float* __restrict__ bn_b,
    const float* __restrict__ fw,
    const float* __restrict__ fb,
    float* __restrict__ out)
{
    __shared__ float acc[64];
    const int p = threadIdx.x;
    if (p < 64) acc[p] = 0.f;
    __syncthreads();

    float x[32];
    const float4* sp = (const float4*)(scores + p * 32);
    #pragma unroll
    for (int i = 0; i < 8; ++i) ((float4*)x)[i] = sp[i];

    float mean = 0.f;
    #pragma unroll
    for (int i = 0; i < 32; ++i) mean += x[i];
    mean *= (1.f / 32.f);
    float var = 0.f;
    #pragma unroll
    for (int i = 0; i < 32; ++i) { const float d = x[i] - mean; var = fmaf(d, d, var); }
    var *= (1.f / 32.f);

    const float scale = (1.f / sqrtf(var + 1e-5f)) * bn_w[p];
    const float shift = bn_b[p];
    const float w0 = fw[p], w1 = fw[PP + p];

    for (int b = 0; b < 32; ++b) {
        const float v = (x[b] - mean) * scale + shift;
        const bool bin = v > 0.f;
        float v0 = bin ? w0 : 0.f;
        float v1 = bin ? w1 : 0.f;
        #pragma unroll
        for (int o = 32; o; o >>= 1) {
            v0 += __shfl_xor(v0, o);
            v1 += __shfl_xor(v1, o);
        }
        if ((threadIdx.x & 63) == 0) {
            atomicAdd(&acc[b * 2 + 0], v0);
            atomicAdd(&acc[b * 2 + 1], v1);
        }
    }
    __syncthreads();
    if (p < 64) out[p] = acc[p] + fb[p & 1];
}

// ---------------------------------------------------------------------------
extern "C" void kernel_launch(void* const* d_in, const int* in_sizes, int n_in,
                              void* d_out, int out_size, void* d_ws, size_t ws_size,
                              hipStream_t stream) {
    const int*   tokens   = (const int*)d_in[0];
    const int*   doc_lens = (const int*)d_in[1];
    const float* emb      = (const float*)d_in[2];
    const float* diags    = (const float*)d_in[3];
    const float* bias     = (const float*)d_in[4];
    const float* eps      = (const float*)d_in[5];
    const float* bnw      = (const float*)d_in[6];
    const float* bnb      = (const float*)d_in[7];
    const float* fw       = (const float*)d_in[8];
    const float* fb       = (const float*)d_in[9];
    float* out = (float*)d_out;

    float* ts     = (float*)d_ws;                    // [4096][7168] = 117.4 MB
    float* scores = ts + (size_t)4096 * NX;          // [512][32]
    _Float16* AhP = (_Float16*)(scores + PP * BB);   // frag-blocked packs
    _Float16* AlP = AhP + (size_t)AT * KT * 512;
    _Float16* BhP = AlP + (size_t)AT * KT * 512;
    _Float16* BlP = BhP + (size_t)BT * KT * 512;

    pack_kernel<<<(AT + BT) * KT * 64 / 256, 256, 0, stream>>>(
        tokens, emb, diags, bias, AhP, AlP, BhP, BlP);
    gemm_kernel<<<dim3(BT / 8, AT / 8), 256, 0, stream>>>(
        AhP, AlP, BhP, BlP, doc_lens, ts);
    scan_kernel<<<dim3(BB, PP / 64), 64, 0, stream>>>(ts, eps, doc_lens, scores);
    finalize_kernel<<<1, 512, 0, stream>>>(scores, bnw, bnb, fw, fb, out);
}

// Round 6
// 202.294 us; speedup vs baseline: 1.1758x; 1.1758x over previous
//
#include <hip/hip_runtime.h>

#define BB 32
#define TT 128
#define PP 512
#define DD 300
#define KT 10      // K chunks of 32 (KP = 320 = 300 data + bias slot + zeros)
#define NX 7168    // P * 14: full column set, native 14-stride scan layout
#define AT 256     // A tiles (4096/16)
#define BT 448     // B tiles (7168/16)
#define NEG -1e30f

typedef _Float16 half8 __attribute__((ext_vector_type(8)));
typedef float floatx4 __attribute__((ext_vector_type(4)));

__device__ __forceinline__ void async_load16(const void* g, void* l) {
    __builtin_amdgcn_global_load_lds(
        (const __attribute__((address_space(1))) void*)g,
        (__attribute__((address_space(3))) void*)l, 16, 0, 0);
}

__device__ __forceinline__ floatx4 mfma16(half8 a, half8 b, floatx4 c) {
    return __builtin_amdgcn_mfma_f32_16x16x32_f16(a, b, c, 0, 0, 0);
}

// ---------------------------------------------------------------------------
// Pack into MFMA-fragment-blocked layout + error-free f16 Dekker split
// (x = hi + lo*2^-12, lo stored *4096). Chunk (tile16, kt32) = 1KB:
// half idx = lane*8+i, row = tile*16+(lane&15), k = kt*32+(lane>>4)*8+i.
// B rows = diags rows 0..7167 directly (all 14 cols; col 13 output is dead
// but writing it keeps C dense 14-stride). K-slot 300 carries bias
// (A side gets exact 1.0); slots 301..319 zero. UNCHANGED from R0.
// ---------------------------------------------------------------------------
__global__ __launch_bounds__(256) void pack_kernel(
    const int* __restrict__ tokens, const float* __restrict__ emb,
    const float* __restrict__ diags, const float* __restrict__ bias,
    _Float16* __restrict__ AhP, _Float16* __restrict__ AlP,
    _Float16* __restrict__ BhP, _Float16* __restrict__ BlP)
{
    const int idx = blockIdx.x * 256 + threadIdx.x;
    if (idx >= (AT + BT) * KT * 64) return;
    const int chunk = idx >> 6;
    const int ln = idx & 63;

    const float* src;
    float kslot;
    _Float16 *dh, *dl;
    int kt;
    if (chunk < AT * KT) {
        const int mt = chunk / KT; kt = chunk - mt * KT;
        const int m = mt * 16 + (ln & 15);
        src = emb + (size_t)tokens[m] * DD;
        kslot = 1.0f;
        dh = AhP + (size_t)chunk * 512 + ln * 8;
        dl = AlP + (size_t)chunk * 512 + ln * 8;
    } else {
        const int c2 = chunk - AT * KT;
        const int nt = c2 / KT; kt = c2 - nt * KT;
        const int n = nt * 16 + (ln & 15);       // srow = n directly
        src = diags + (size_t)n * DD;
        kslot = bias[n];
        dh = BhP + (size_t)c2 * 512 + ln * 8;
        dl = BlP + (size_t)c2 * 512 + ln * 8;
    }

    const int k0 = kt * 32 + (ln >> 4) * 8;
    float v[8];
    if (k0 + 8 <= DD) {
        float4 a = *(const float4*)(src + k0);
        float4 b = *(const float4*)(src + k0 + 4);
        v[0] = a.x; v[1] = a.y; v[2] = a.z; v[3] = a.w;
        v[4] = b.x; v[5] = b.y; v[6] = b.z; v[7] = b.w;
    } else {
        #pragma unroll
        for (int i = 0; i < 8; ++i) {
            const int k = k0 + i;
            v[i] = (k < DD) ? src[k] : (k == DD ? kslot : 0.f);
        }
    }
    half8 h, l;
    #pragma unroll
    for (int i = 0; i < 8; ++i) {
        h[i] = (_Float16)v[i];
        l[i] = (_Float16)((v[i] - (float)h[i]) * 4096.f);
    }
    *(half8*)dh = h;
    *(half8*)dl = l;
}

// ---------------------------------------------------------------------------
// GEMM (R6 = R0 proven schedule with BK=64 staging).
// C[m][n] = sum_k A[m][k]*B[n][k] (bias folded into k=300).
// R5 post-mortem: removing the LDS stage exposed per-j B-load latency
// (gemm 98us, VALUBusy 10%) — the barrier+LDS path was load-bearing.
// R6 keeps R0's structure EXACTLY but stages TWO K-chunks per buffer:
// Bs[2][2][2][8][512] = 64KB (2 blocks/CU -> 128KB <= 160KB, occupancy
// unchanged; we're register-bound at 2 blocks regardless). 5 barrier
// drains instead of 10 — the diagnosed ~30us vmcnt(0)-drain stall halves.
// Phase body = R0 body twice; MFMA order per accumulator identical ->
// bit-identical C. Epilogue-only dead-row store guard kept from R5
// (post-loop, cannot perturb the K-loop schedule): block rows = t 0..127
// of batch element b = blockIdx.y; tiles with t0 >= dl are never read by
// the scan -> skip their stores. Only wave wm=1 ever branches (dl >= 64).
// ---------------------------------------------------------------------------
__global__ __launch_bounds__(256, 2) void gemm_kernel(
    const _Float16* __restrict__ AhP, const _Float16* __restrict__ AlP,
    const _Float16* __restrict__ BhP, const _Float16* __restrict__ BlP,
    const int* __restrict__ doc_lens,
    float* __restrict__ C)
{
    __shared__ __align__(16) _Float16 Bs[2][2][2][8][512]; // [dbuf][q][h/l][nt][frag]

    const int tid = threadIdx.x;
    const int w = tid >> 6, ln = tid & 63;
    const int n0t = blockIdx.x * 8, m0t = blockIdx.y * 8;
    const int wm = w & 1, wn = w >> 1;

    const int dl = doc_lens[blockIdx.y];   // rows of this block = t 0..127 of b

    floatx4 acc0[4][4], acc1[4][4];
    #pragma unroll
    for (int i = 0; i < 4; ++i)
        #pragma unroll
        for (int j = 0; j < 4; ++j) {
            acc0[i][j] = (floatx4){0.f, 0.f, 0.f, 0.f};
            acc1[i][j] = (floatx4){0.f, 0.f, 0.f, 0.f};
        }

    half8 ah[2][4], al[2][4];

    auto loadA = [&](int kt, int pb) {
        #pragma unroll
        for (int i = 0; i < 4; ++i) {
            const size_t ch = ((size_t)(m0t + wm * 4 + i) * KT + kt) * 512 + ln * 8;
            ah[pb][i] = *(const half8*)(AhP + ch);
            al[pb][i] = *(const half8*)(AlP + ch);
        }
    };
    // stage kt0 and kt0+1 into buffer buf (8 async ops per wave)
    auto stageB2 = [&](int kt0, int buf) {
        #pragma unroll
        for (int q = 0; q < 2; ++q)
            #pragma unroll
            for (int s = 0; s < 2; ++s) {
                const int nt = w + s * 4;   // wave w stages ntiles {w, w+4}
                const size_t ch = ((size_t)(n0t + nt) * KT + (kt0 + q)) * 512 + ln * 8;
                async_load16(BhP + ch, &Bs[buf][q][0][nt][0]);
                async_load16(BlP + ch, &Bs[buf][q][1][nt][0]);
            }
    };

    stageB2(0, 0);
    loadA(0, 0);
    __syncthreads();

    #pragma unroll
    for (int ph = 0; ph < 5; ++ph) {
        const int cb = ph & 1, nb = cb ^ 1;
        if (ph + 1 < 5) stageB2(2 * ph + 2, nb);
        #pragma unroll
        for (int q = 0; q < 2; ++q) {
            const int kt = 2 * ph + q;
            const int ab = kt & 1;
            if (kt + 1 < KT) loadA(kt + 1, ab ^ 1);
            #pragma unroll
            for (int j = 0; j < 4; ++j) {
                const half8 bh = *(const half8*)&Bs[cb][q][0][wn * 4 + j][ln * 8];
                const half8 bl = *(const half8*)&Bs[cb][q][1][wn * 4 + j][ln * 8];
                #pragma unroll
                for (int i = 0; i < 4; ++i) {
                    acc0[i][j] = mfma16(ah[ab][i], bh, acc0[i][j]);
                    acc1[i][j] = mfma16(ah[ab][i], bl, acc1[i][j]);
                    acc1[i][j] = mfma16(al[ab][i], bh, acc1[i][j]);
                }
            }
        }
        __syncthreads();
    }

    // epilogue: C/D layout col(n)=lane&15, row(m)=(lane>>4)*4+reg.
    // store guard: tile i covers t in [(wm*4+i)*16, +16); dead iff t0 >= dl.
    #pragma unroll
    for (int j = 0; j < 4; ++j) {
        const int n = (n0t + wn * 4 + j) * 16 + (ln & 15);
        #pragma unroll
        for (int i = 0; i < 4; ++i) {
            if ((wm * 4 + i) * 16 < dl) {
                const int mb = (m0t + wm * 4 + i) * 16 + (ln >> 4) * 4;
                #pragma unroll
                for (int r = 0; r < 4; ++r)
                    C[(size_t)(mb + r) * NX + n] =
                        acc0[i][j][r] + acc1[i][j][r] * (1.0f / 4096.0f);
            }
        }
    }
}

// ---------------------------------------------------------------------------
// Max-sum scan (proven structure, UNCHANGED from R0 except the t-clamp).
// One thread per (b,p); 14-float 8B-aligned rows, 7x float2 loads, depth-4
// prefetch with STATIC slot indices; dl block-uniform. Rows t >= dl may be
// unwritten (gemm store guard) but are never consumed.
// v[0..6]=self-loop (diag0 l0..6), v[7..12]=main (diag1 l0..5), v[13] dead.
// ---------------------------------------------------------------------------
__global__ __launch_bounds__(64) void scan_kernel(
    const float* __restrict__ ts,
    const float* __restrict__ epsilons,
    const int* __restrict__ doc_lens,
    float* __restrict__ scores)
{
    const int b = blockIdx.x;
    const int p = blockIdx.y * 64 + threadIdx.x;
    const int dl = doc_lens[b];   // in [64, 128]

    float e[6];
    #pragma unroll
    for (int i = 0; i < 6; ++i) e[i] = epsilons[p * 6 + i];

    const float* base = ts + (size_t)b * TT * NX + p * 14;

    float h0 = 0.f, h1 = NEG, h2 = NEG, h3 = NEG, h4 = NEG, h5 = NEG, h6 = NEG;
    float sc = NEG;
    const bool end5 = (p < 256);

    float2 buf[4][7];

    auto load = [&](int slot, int t) {
        const float2* s = (const float2*)(base + (size_t)t * NX);
        #pragma unroll
        for (int i = 0; i < 7; ++i) buf[slot][i] = s[i];
    };
    auto step = [&](int slot) {
        const float2* v = buf[slot];
        float ae0 = h0;
        float ae1 = fmaxf(h1, h0 + e[0]);
        float ae2 = fmaxf(h2, h1 + e[1]);
        float ae3 = fmaxf(h3, h2 + e[2]);
        float ae4 = fmaxf(h4, h3 + e[3]);
        float ae5 = fmaxf(h5, h4 + e[4]);
        float ae6 = fmaxf(h6, h5 + e[5]);
        h0 = fmaxf(0.f,            ae0 + v[0].x);
        h1 = fmaxf(ae0 + v[3].y,   ae1 + v[0].y);
        h2 = fmaxf(ae1 + v[4].x,   ae2 + v[1].x);
        h3 = fmaxf(ae2 + v[4].y,   ae3 + v[1].y);
        h4 = fmaxf(ae3 + v[5].x,   ae4 + v[2].x);
        h5 = fmaxf(ae4 + v[5].y,   ae5 + v[2].y);
        h6 = fmaxf(ae5 + v[6].x,   ae6 + v[3].x);
        sc = fmaxf(sc, end5 ? h5 : h6);   // every executed step has t < dl
    };

    #pragma unroll
    for (int j = 0; j < 4; ++j) load(j, j);

    int tb = 0;
    for (; tb + 4 <= dl; tb += 4) {
        #pragma unroll
        for (int j = 0; j < 4; ++j) {
            step(j);
            const int t = tb + j + 4;
            load(j, t > 127 ? 127 : t);   // clamp: slots past dl never consumed
        }
    }
    const int rem = dl - tb;       // 0..3, block-uniform
    #pragma unroll
    for (int j = 0; j < 3; ++j)
        if (j < rem) step(j);

    scores[p * BB + b] = sc;
}

// ---------------------------------------------------------------------------
// BatchNorm (batch stats) + sign(relu) + final linear. One block. UNCHANGED.
// ---------------------------------------------------------------------------
__global__ __launch_bounds__(512) void finalize_kernel(
    const float* __restrict__ scores,
    const float* __restrict__ bn_w,
    const float* __restrict__ bn_b,
    const float* __restrict__ fw,
    const float* __restrict__ fb,
    float* __restrict__ out)
{
    __shared__ float acc[64];
    const int p = threadIdx.x;
    if (p < 64) acc[p] = 0.f;
    __syncthreads();

    float x[32];
    const float4* sp = (const float4*)(scores + p * 32);
    #pragma unroll
    for (int i = 0; i < 8; ++i) ((float4*)x)[i] = sp[i];

    float mean = 0.f;
    #pragma unroll
    for (int i = 0; i < 32; ++i) mean += x[i];
    mean *= (1.f / 32.f);
    float var = 0.f;
    #pragma unroll
    for (int i = 0; i < 32; ++i) { const float d = x[i] - mean; var = fmaf(d, d, var); }
    var *= (1.f / 32.f);

    const float scale = (1.f / sqrtf(var + 1e-5f)) * bn_w[p];
    const float shift = bn_b[p];
    const float w0 = fw[p], w1 = fw[PP + p];

    for (int b = 0; b < 32; ++b) {
        const float v = (x[b] - mean) * scale + shift;
        const bool bin = v > 0.f;
        float v0 = bin ? w0 : 0.f;
        float v1 = bin ? w1 : 0.f;
        #pragma unroll
        for (int o = 32; o; o >>= 1) {
            v0 += __shfl_xor(v0, o);
            v1 += __shfl_xor(v1, o);
        }
        if ((threadIdx.x & 63) == 0) {
            atomicAdd(&acc[b * 2 + 0], v0);
            atomicAdd(&acc[b * 2 + 1], v1);
        }
    }
    __syncthreads();
    if (p < 64) out[p] = acc[p] + fb[p & 1];
}

// ---------------------------------------------------------------------------
extern "C" void kernel_launch(void* const* d_in, const int* in_sizes, int n_in,
                              void* d_out, int out_size, void* d_ws, size_t ws_size,
                              hipStream_t stream) {
    const int*   tokens   = (const int*)d_in[0];
    const int*   doc_lens = (const int*)d_in[1];
    const float* emb      = (const float*)d_in[2];
    const float* diags    = (const float*)d_in[3];
    const float* bias     = (const float*)d_in[4];
    const float* eps      = (const float*)d_in[5];
    const float* bnw      = (const float*)d_in[6];
    const float* bnb      = (const float*)d_in[7];
    const float* fw       = (const float*)d_in[8];
    const float* fb       = (const float*)d_in[9];
    float* out = (float*)d_out;

    float* ts     = (float*)d_ws;                    // [4096][7168] = 117.4 MB
    float* scores = ts + (size_t)4096 * NX;          // [512][32]
    _Float16* AhP = (_Float16*)(scores + PP * BB);   // frag-blocked packs
    _Float16* AlP = AhP + (size_t)AT * KT * 512;
    _Float16* BhP = AlP + (size_t)AT * KT * 512;
    _Float16* BlP = BhP + (size_t)BT * KT * 512;

    pack_kernel<<<(AT + BT) * KT * 64 / 256, 256, 0, stream>>>(
        tokens, emb, diags, bias, AhP, AlP, BhP, BlP);
    gemm_kernel<<<dim3(BT / 8, AT / 8), 256, 0, stream>>>(
        AhP, AlP, BhP, BlP, doc_lens, ts);
    scan_kernel<<<dim3(BB, PP / 64), 64, 0, stream>>>(ts, eps, doc_lens, scores);
    finalize_kernel<<<1, 512, 0, stream>>>(scores, bnw, bnb, fw, fb, out);
}